// Round 14
// baseline (1004.045 us; speedup 1.0000x reference)
//
#include <hip/hip_runtime.h>
#include <math.h>

#define B_ 2
#define T_ 12
#define N_ 207
#define DM_ 64
#define H_ 4
#define DK_ 16
#define DH_ 256
#define MTOK 4968       // B*T*N
#define MTOKP 4992      // padded rows in hid buffers; last GEMM m-tile over-reads within d_ws (guarded)
#define OUT2 12288      // 3*H*DK*DM
#define QKVC 192        // 3*H*DK

typedef __bf16 bf16x8 __attribute__((ext_vector_type(8)));
typedef float f32x4 __attribute__((ext_vector_type(4)));
typedef unsigned short ushortx8 __attribute__((ext_vector_type(8)));

__device__ __forceinline__ unsigned short f2bf(float f) {
    union { float f; unsigned u; } v; v.f = f;
    unsigned r = v.u + 0x7fffu + ((v.u >> 16) & 1u);   // RNE
    return (unsigned short)(r >> 16);
}
__device__ __forceinline__ float bf2f(unsigned short b) {
    union { unsigned u; float f; } v; v.u = ((unsigned)b) << 16; return v.f;
}
__device__ __forceinline__ void gll16(const void* g, void* l) {
    __builtin_amdgcn_global_load_lds((const __attribute__((address_space(1))) void*)g,
                                     (__attribute__((address_space(3))) void*)l, 16, 0, 0);
}

// ---------------- Kernel A: hid hi/lo bf16 = split(relu(c_inputs @ ml_w1 + b1)) ----------------
__global__ __launch_bounds__(256) void k_hid2(const float* __restrict__ cin,
                                              const float* __restrict__ w1,
                                              const float* __restrict__ b1,
                                              unsigned short* __restrict__ hh,
                                              unsigned short* __restrict__ hl) {
    __shared__ float cs[16][DM_];
    const int t0 = blockIdx.x * 16;
    const int tid = threadIdx.x;
    #pragma unroll
    for (int r = 0; r < 4; ++r) {
        int idx = r * 256 + tid;
        int t = idx >> 6, d = idx & 63;
        int tok = t0 + t;
        cs[t][d] = (tok < MTOK) ? cin[(size_t)tok * DM_ + d] : 0.f;
    }
    __syncthreads();
    float a[16];
    #pragma unroll
    for (int t = 0; t < 16; ++t) a[t] = 0.f;
    for (int d = 0; d < DM_; ++d) {
        float wv = w1[d * DH_ + tid];
        #pragma unroll
        for (int t = 0; t < 16; ++t) a[t] = fmaf(cs[t][d], wv, a[t]);
    }
    float b = b1[tid];
    #pragma unroll
    for (int t = 0; t < 16; ++t) {
        int tok = t0 + t;
        float val = (tok < MTOK) ? fmaxf(a[t] + b, 0.f) : 0.f;
        unsigned short hi = f2bf(val);
        hh[(size_t)tok * DH_ + tid] = hi;
        hl[(size_t)tok * DH_ + tid] = f2bf(val - bf2f(hi));
    }
}

// ---------------- Kernel B: transpose + split w2 [256 x 12288] -> w2t_hi/lo [12288 x 256] bf16 ----------------
__global__ __launch_bounds__(256) void k_split(const float* __restrict__ w2,
                                               unsigned short* __restrict__ th,
                                               unsigned short* __restrict__ tl) {
    __shared__ float tbuf[64][72];
    const int tid = threadIdx.x;
    const int c0 = blockIdx.x * 64;
    const int j0 = blockIdx.y * 64;
    #pragma unroll
    for (int r = 0; r < 4; ++r) {
        int idx = r * 256 + tid;
        int j = idx >> 4, c4 = idx & 15;
        float4 v = *reinterpret_cast<const float4*>(w2 + (size_t)(j0 + j) * OUT2 + c0 + c4 * 4);
        *reinterpret_cast<float4*>(&tbuf[j][c4 * 4]) = v;
    }
    __syncthreads();
    #pragma unroll
    for (int r = 0; r < 2; ++r) {
        int slot = r * 256 + tid;
        int c = slot >> 3, j8 = slot & 7;
        ushortx8 Hv, Lv;
        #pragma unroll
        for (int e = 0; e < 8; ++e) {
            float f = tbuf[j8 * 8 + e][c];
            unsigned short h = f2bf(f);
            Hv[e] = h;
            Lv[e] = f2bf(f - bf2f(h));
        }
        size_t off = (size_t)(c0 + c) * DH_ + j0 + j8 * 8;
        *reinterpret_cast<ushortx8*>(th + off) = Hv;
        *reinterpret_cast<ushortx8*>(tl + off) = Lv;
    }
}

// ---------------- Kernel C: split-bf16 MFMA GEMM — 256x256 tile, 16 waves (1024 thr), 2 blocks/CU ----------------
// A[~5120 x 256] (hid hi/lo; over-read rows discarded), B[12288 x 256] (w2t hi/lo, K-major).
// Wave grid 4m x 4n; wave-tile 64x64 -> per-thread regs identical to R13's measured 64 VGPR (acc[4][4]).
// 960 blocks = 8 XCDs x (20 m x 6 n); B panel (1.57 MB) L2-resident. Staged bytes 497 MB (0.51x R13).
// 64 KB single-buffer LDS -> 2 blocks/CU; coalesced full-line staging (one gll16 covers the whole array tile)
// with both-sides chunk XOR-swizzle (R10/R13-proven).
__global__ __launch_bounds__(1024, 8) void k_gemm(const unsigned short* __restrict__ Ah,
                                                  const unsigned short* __restrict__ Al,
                                                  const unsigned short* __restrict__ Bh,
                                                  const unsigned short* __restrict__ Bl,
                                                  const float* __restrict__ b2,
                                                  const float* __restrict__ x,
                                                  float* __restrict__ qkv) {
    __shared__ __align__(16) unsigned short sAh[8192], sAl[8192];   // 256 rows x 32 k
    __shared__ __align__(16) unsigned short sBh[8192], sBl[8192];
    const int tid = threadIdx.x;
    // XCD-column swizzle: 960 = 8 XCDs x (20 m x 6 n); n fastest within a chunk
    const int bid = blockIdx.x;
    const int xcd = bid & 7;
    const int r_ = bid >> 3;                      // 0..119
    const int m0 = (r_ / 6) * 256;                // 20 m-tiles (last over-reads, guarded)
    const int n0 = (xcd * 6 + (r_ % 6)) * 256;    // 6 n-tiles per XCD
    const int wid = tid >> 6;                     // 0..15
    const int lane = tid & 63;
    const int l15 = lane & 15, l4 = lane >> 4;
    const int wm = wid >> 2, wn = wid & 3;        // 4m x 4n wave grid; wave-tile 64x64

    // ---- coalesced staging: row = tid>>2 (0..255), chunk = tid&3 (one gll16 per array per K-step)
    const int srow = tid >> 2;
    const int sch  = tid & 3;
    const int sswz = (srow & 3) ^ ((srow >> 2) & 3);
    const int gch  = sch ^ sswz;                  // pre-swizzled global chunk (same 64B line)
    const unsigned short* pAh = Ah + (size_t)(m0 + srow) * DH_ + gch * 8;
    const unsigned short* pAl = Al + (size_t)(m0 + srow) * DH_ + gch * 8;
    const unsigned short* pBh = Bh + (size_t)(n0 + srow) * DH_ + gch * 8;
    const unsigned short* pBl = Bl + (size_t)(n0 + srow) * DH_ + gch * 8;
    const int lb = wid * 512;                     // wave-uniform LDS ushort base (64 lanes x 8)

    // ---- fragment-read swizzle (depends only on l15)
    const int rswz = (l15 & 3) ^ ((l15 >> 2) & 3);
    const int chR  = (l4 ^ rswz) * 8;             // ushort offset of the 16B chunk

    f32x4 acc[4][4];
    const f32x4 zero = {0.f, 0.f, 0.f, 0.f};
    #pragma unroll
    for (int i = 0; i < 4; ++i)
        #pragma unroll
        for (int j = 0; j < 4; ++j) acc[i][j] = zero;

    for (int ks = 0; ks < 8; ++ks) {
        gll16(pAh, &sAh[lb]);
        gll16(pAl, &sAl[lb]);
        gll16(pBh, &sBh[lb]);
        gll16(pBl, &sBl[lb]);
        pAh += 32; pAl += 32; pBh += 32; pBl += 32;   // advance BK=32 k-elems
        __syncthreads();                  // drains vmcnt + lgkm; buffer ready

        bf16x8 ah[4], al[4];
        #pragma unroll
        for (int mi = 0; mi < 4; ++mi) {
            int ma = (wm * 64 + mi * 16 + l15) * 32 + chR;
            ah[mi] = *reinterpret_cast<const bf16x8*>(&sAh[ma]);
            al[mi] = *reinterpret_cast<const bf16x8*>(&sAl[ma]);
        }
        #pragma unroll
        for (int ni = 0; ni < 4; ++ni) {
            int nb = (wn * 64 + ni * 16 + l15) * 32 + chR;
            bf16x8 bh = *reinterpret_cast<const bf16x8*>(&sBh[nb]);
            bf16x8 bl = *reinterpret_cast<const bf16x8*>(&sBl[nb]);
            #pragma unroll
            for (int mi = 0; mi < 4; ++mi)
                acc[mi][ni] = __builtin_amdgcn_mfma_f32_16x16x32_bf16(ah[mi], bh, acc[mi][ni], 0, 0, 0);
            #pragma unroll
            for (int mi = 0; mi < 4; ++mi)
                acc[mi][ni] = __builtin_amdgcn_mfma_f32_16x16x32_bf16(ah[mi], bl, acc[mi][ni], 0, 0, 0);
            #pragma unroll
            for (int mi = 0; mi < 4; ++mi)
                acc[mi][ni] = __builtin_amdgcn_mfma_f32_16x16x32_bf16(al[mi], bh, acc[mi][ni], 0, 0, 0);
        }
        __syncthreads();                  // LDS reads done; safe to overwrite next iter
    }

    // epilogue: wave's 64 n-columns = one c-block; contract against x over d
    const int cg = (n0 >> 6) + wn;        // global c index (0..191)
    float b2v[4];
    #pragma unroll
    for (int ni = 0; ni < 4; ++ni) b2v[ni] = b2[cg * 64 + ni * 16 + l15];
    #pragma unroll
    for (int mi = 0; mi < 4; ++mi) {
        #pragma unroll
        for (int r = 0; r < 4; ++r) {
            int rl = wm * 64 + mi * 16 + l4 * 4 + r;   // C/D: row=(lane>>4)*4+reg, col=lane&15
            int gm = m0 + rl;
            int gmc = gm < MTOK ? gm : MTOK - 1;
            float v = 0.f;
            #pragma unroll
            for (int ni = 0; ni < 4; ++ni)
                v = fmaf(acc[mi][ni][r] + b2v[ni], x[(size_t)gmc * DM_ + ni * 16 + l15], v);
            #pragma unroll
            for (int sw = 1; sw < 16; sw <<= 1) v += __shfl_xor(v, sw, 16);
            if (l15 == 0 && gm < MTOK) qkv[(size_t)gm * QKVC + cg] = v;
        }
    }
}

// ---------------- Kernel D: retention + GroupNorm + 3*tanh — one wave per (b,n,h), no barriers ----------------
__global__ __launch_bounds__(256) void k_ret4(const float* __restrict__ qkv,
                                              float* __restrict__ xt) {
    const int tid = threadIdx.x;
    const int g = tid >> 6, lane = tid & 63;
    const int n = blockIdx.x * 4 + g;
    const int h = blockIdx.y;
    const int b = blockIdx.z;
    const bool act = (n < N_);
    __shared__ float Q[4][T_][DK_ + 1], K[4][T_][DK_ + 1], V[4][T_][DK_ + 1];
    __shared__ float ret[4][T_][T_ + 1];
    __shared__ float den[4][T_];
    if (act) {
        for (int idx = lane; idx < T_ * DK_; idx += 64) {
            int t = idx >> 4, k = idx & 15;
            size_t base = ((size_t)((b * T_ + t) * N_ + n)) * QKVC + h * DK_ + k;
            Q[g][t][k] = qkv[base];
            K[g][t][k] = qkv[base + 64];
            V[g][t][k] = qkv[base + 128];
        }
        const float r = 1.f - exp2f(-5.f - (float)h);
        for (int p = lane; p < T_ * T_; p += 64) {
            int t = p / T_, s = p - t * T_;
            float val = 0.f;
            if (s <= t) {
                float dot = 0.f;
                #pragma unroll
                for (int k = 0; k < DK_; ++k) dot = fmaf(Q[g][t][k], K[g][s][k], dot);
                float sum = 0.f, rp = 1.f;
                for (int i = 0; i <= t; ++i) { sum += rp; rp *= r; }
                float Dv = powf(r, (float)(t - s)) / sqrtf(sum);
                val = dot * 0.25f * cosf((float)(t - s)) * Dv;
            }
            ret[g][t][s] = val;
        }
        if (lane < T_) {
            float sm = 0.f;
            for (int j = 0; j < T_; ++j) sm += ret[g][lane][j];
            den[g][lane] = fmaxf(fabsf(sm), 1.f);
        }
        for (int idx = lane; idx < T_ * DK_; idx += 64) {
            int t = idx >> 4, k = idx & 15;
            float o = 0.f;
            for (int s = 0; s <= t; ++s) o = fmaf(ret[g][t][s], V[g][s][k], o);
            o /= den[g][t];
            float mu = o;
            #pragma unroll
            for (int w = 8; w >= 1; w >>= 1) mu += __shfl_xor(mu, w, 16);
            mu *= (1.f / 16.f);
            float dv = o - mu;
            float var = dv * dv;
            #pragma unroll
            for (int w = 8; w >= 1; w >>= 1) var += __shfl_xor(var, w, 16);
            var *= (1.f / 16.f);
            float val = dv / sqrtf(var);
            if (isnan(val)) val = 0.f;
            val = 3.f * tanhf(val);
            xt[((size_t)((b * T_ + t) * N_ + n)) * DM_ + h * DK_ + k] = val;
        }
    }
}

// ---------------- Kernel E: GDC + swish + out-proj + residual + LayerNorm — one wave per token ----------------
__global__ __launch_bounds__(256) void k_out4(const float* __restrict__ xt,
                                              const float* __restrict__ in,
                                              const float* __restrict__ gw1,
                                              const float* __restrict__ gw2,
                                              const float* __restrict__ wgw,
                                              const float* __restrict__ wgb,
                                              const float* __restrict__ wow,
                                              const float* __restrict__ wob,
                                              const float* __restrict__ lng,
                                              const float* __restrict__ lnb,
                                              float* __restrict__ out) {
    const int tid = threadIdx.x;
    const int w = tid >> 6;
    const int m = tid & 63;
    const int tok = blockIdx.x * 4 + w;
    const bool act = tok < MTOK;
    const int tokc = act ? tok : MTOK - 1;
    __shared__ float xsh[4][DM_], insh[4][DM_], zsh[4][DM_];
    xsh[w][m]  = xt[(size_t)tokc * DM_ + m];
    insh[w][m] = in[(size_t)tokc * DM_ + m];
    float ah[H_], sh[H_];
    #pragma unroll
    for (int h = 0; h < H_; ++h) {
        float a = 0.f, s = 0.f;
        #pragma unroll
        for (int k = 0; k < DK_; ++k) {
            float xv = xsh[w][h * DK_ + k];
            a = fmaf(xv, gw1[(h * DK_ + k) * DM_ + m], a);
            s = fmaf(xv, gw2[(h * DK_ + k) * DM_ + m], s);
        }
        ah[h] = a;
        sh[h] = fmaxf(s, 0.f);
    }
    float mx = fmaxf(fmaxf(sh[0], sh[1]), fmaxf(sh[2], sh[3]));
    float e0 = expf(sh[0] - mx), e1 = expf(sh[1] - mx);
    float e2 = expf(sh[2] - mx), e3 = expf(sh[3] - mx);
    float esum = e0 + e1 + e2 + e3;
    float g = (ah[0] * e0 + ah[1] * e1 + ah[2] * e2 + ah[3] * e3) / esum;
    float z = 0.f;
    for (int d = 0; d < DM_; ++d) z = fmaf(insh[w][d], wgw[d * DM_ + m], z);
    z += wgb[m];
    z *= g;
    z = z / (1.f + expf(-z));
    zsh[w][m] = z;
    float o = 0.f;
    for (int d = 0; d < DM_; ++d) o = fmaf(zsh[w][d], wow[d * DM_ + m], o);
    o += wob[m];
    float y = o + insh[w][m];
    float mu = y;
    #pragma unroll
    for (int xm = 32; xm >= 1; xm >>= 1) mu += __shfl_xor(mu, xm, 64);
    mu *= (1.f / 64.f);
    float dv = y - mu;
    float var = dv * dv;
    #pragma unroll
    for (int xm = 32; xm >= 1; xm >>= 1) var += __shfl_xor(var, xm, 64);
    var *= (1.f / 64.f);
    float res = dv / sqrtf(var + 1e-5f) * lng[m] + lnb[m];
    if (act) out[(size_t)tok * DM_ + m] = res;
}

// ---------------- fallback fp32 kernels (old path, if workspace too small) ----------------
__global__ __launch_bounds__(256) void k_hid(const float* __restrict__ cin,
                                             const float* __restrict__ w1,
                                             const float* __restrict__ b1,
                                             float* __restrict__ hid) {
    __shared__ float cs[4][DM_];
    const int t0 = blockIdx.x * 4;
    const int tid = threadIdx.x;
    {
        int t = tid >> 6, d = tid & 63;
        cs[t][d] = cin[(size_t)(t0 + t) * DM_ + d];
    }
    __syncthreads();
    float a0 = 0.f, a1 = 0.f, a2 = 0.f, a3 = 0.f;
    for (int d = 0; d < DM_; ++d) {
        float w = w1[d * DH_ + tid];
        a0 = fmaf(cs[0][d], w, a0);
        a1 = fmaf(cs[1][d], w, a1);
        a2 = fmaf(cs[2][d], w, a2);
        a3 = fmaf(cs[3][d], w, a3);
    }
    float b = b1[tid];
    hid[(size_t)(t0 + 0) * DH_ + tid] = fmaxf(a0 + b, 0.f);
    hid[(size_t)(t0 + 1) * DH_ + tid] = fmaxf(a1 + b, 0.f);
    hid[(size_t)(t0 + 2) * DH_ + tid] = fmaxf(a2 + b, 0.f);
    hid[(size_t)(t0 + 3) * DH_ + tid] = fmaxf(a3 + b, 0.f);
}

#define BM 192
#define BN 96
template <int KS>
__global__ __launch_bounds__(256, 2) void k_qkv(const float* __restrict__ x,
                                                const float* __restrict__ hid,
                                                const float* __restrict__ w2,
                                                const float* __restrict__ b2,
                                                float* __restrict__ part) {
    constexpr int JPB = DH_ / KS;
    __shared__ float4 xs4[BM * 16];
    __shared__ float4 ws4[BN * 16];
    const int tid = threadIdx.x;
    const int m0 = blockIdx.x * BM;
    const int c0 = blockIdx.y * BN;
    const int kz = blockIdx.z;
    const int cidx = tid & 15;
    const int midx = tid >> 4;
    #pragma unroll
    for (int i = 0; i < 12; ++i) {
        int e4 = tid + 256 * i;
        int m = e4 >> 4;
        int d4 = e4 & 15;
        int gm = m0 + m;
        float4 v = make_float4(0.f, 0.f, 0.f, 0.f);
        if (gm < MTOK) v = *reinterpret_cast<const float4*>(x + (size_t)gm * DM_ + d4 * 4);
        xs4[m * 16 + (d4 ^ (m & 15))] = v;
    }
    float acc[12][6];
    #pragma unroll
    for (int i = 0; i < 12; ++i)
        #pragma unroll
        for (int q = 0; q < 6; ++q) acc[i][q] = 0.f;
    const int jn = (kz == 0) ? (JPB + 1) : JPB;
    float4 st[6];
    {
        const float* src = w2 + (size_t)(kz * JPB) * OUT2 + c0 * DM_;
        #pragma unroll
        for (int i = 0; i < 6; ++i)
            st[i] = *reinterpret_cast<const float4*>(src + (tid + 256 * i) * 4);
    }
    #pragma unroll
    for (int i = 0; i < 6; ++i) {
        int t4 = tid + 256 * i;
        int c = t4 >> 4;
        int d4 = t4 & 15;
        ws4[c * 16 + (d4 ^ (c & 15))] = st[i];
    }
    __syncthreads();
    for (int jj = 0; jj < jn; ++jj) {
        const bool have_next = (jj + 1 < jn);
        if (have_next) {
            const bool nb = (kz == 0) && (jj + 1 == JPB);
            const float* src = nb ? (b2 + c0 * DM_)
                                  : (w2 + (size_t)(kz * JPB + jj + 1) * OUT2 + c0 * DM_);
            #pragma unroll
            for (int i = 0; i < 6; ++i)
                st[i] = *reinterpret_cast<const float4*>(src + (tid + 256 * i) * 4);
        }
        const bool bias_cur = (kz == 0) && (jj == JPB);
        const int jg = kz * JPB + jj;
        float hv[12];
        #pragma unroll
        for (int i = 0; i < 12; ++i) {
            int gm = m0 + midx + 16 * i;
            hv[i] = bias_cur ? 1.f : ((gm < MTOK) ? hid[(size_t)gm * DH_ + jg] : 0.f);
        }
        for (int d4 = 0; d4 < 16; ++d4) {
            float4 xa[12];
            #pragma unroll
            for (int i = 0; i < 12; ++i) {
                float4 v = xs4[(midx + 16 * i) * 16 + (d4 ^ midx)];
                v.x *= hv[i]; v.y *= hv[i]; v.z *= hv[i]; v.w *= hv[i];
                xa[i] = v;
            }
            #pragma unroll
            for (int q = 0; q < 6; ++q) {
                float4 wv = ws4[(cidx + 16 * q) * 16 + (d4 ^ cidx)];
                #pragma unroll
                for (int i = 0; i < 12; ++i) {
                    float t = acc[i][q];
                    t = fmaf(xa[i].x, wv.x, t);
                    t = fmaf(xa[i].y, wv.y, t);
                    t = fmaf(xa[i].z, wv.z, t);
                    t = fmaf(xa[i].w, wv.w, t);
                    acc[i][q] = t;
                }
            }
        }
        __syncthreads();
        if (have_next) {
            #pragma unroll
            for (int i = 0; i < 6; ++i) {
                int t4 = tid + 256 * i;
                int c = t4 >> 4;
                int d4 = t4 & 15;
                ws4[c * 16 + (d4 ^ (c & 15))] = st[i];
            }
        }
        __syncthreads();
    }
    float* dst = part + (size_t)kz * MTOK * QKVC;
    #pragma unroll
    for (int i = 0; i < 12; ++i) {
        int gm = m0 + midx + 16 * i;
        if (gm < MTOK) {
            #pragma unroll
            for (int q = 0; q < 6; ++q)
                dst[(size_t)gm * QKVC + c0 + cidx + 16 * q] = acc[i][q];
        }
    }
}

template <int KS>
__global__ __launch_bounds__(64) void k_ret(const float* __restrict__ part,
                                            float* __restrict__ xt) {
    const int n = blockIdx.x;
    const int h = blockIdx.y;
    const int b = blockIdx.z;
    const int tid = threadIdx.x;
    __shared__ float Q[T_][DK_ + 1], K[T_][DK_ + 1], V[T_][DK_ + 1];
    __shared__ float ret[T_][T_ + 1];
    __shared__ float den[T_];
    for (int idx = tid; idx < T_ * DK_; idx += 64) {
        int t = idx >> 4, k = idx & 15;
        size_t base = ((size_t)((b * T_ + t) * N_ + n)) * QKVC + h * DK_ + k;
        float q = 0.f, kk = 0.f, v = 0.f;
        #pragma unroll
        for (int p = 0; p < KS; ++p) {
            size_t off = (size_t)p * MTOK * QKVC + base;
            q  += part[off];
            kk += part[off + 64];
            v  += part[off + 128];
        }
        Q[t][k] = q; K[t][k] = kk; V[t][k] = v;
    }
    __syncthreads();
    const float r = 1.f - exp2f(-5.f - (float)h);
    for (int p = tid; p < T_ * T_; p += 64) {
        int t = p / T_, s = p - t * T_;
        float val = 0.f;
        if (s <= t) {
            float dot = 0.f;
            #pragma unroll
            for (int k = 0; k < DK_; ++k) dot = fmaf(Q[t][k], K[s][k], dot);
            float sum = 0.f, rp = 1.f;
            for (int i = 0; i <= t; ++i) { sum += rp; rp *= r; }
            float Dv = powf(r, (float)(t - s)) / sqrtf(sum);
            val = dot * 0.25f * cosf((float)(t - s)) * Dv;
        }
        ret[t][s] = val;
    }
    __syncthreads();
    if (tid < T_) {
        float sm = 0.f;
        for (int j = 0; j < T_; ++j) sm += ret[tid][j];
        den[tid] = fmaxf(fabsf(sm), 1.f);
    }
    __syncthreads();
    for (int idx = tid; idx < T_ * DK_; idx += 64) {
        int t = idx >> 4, k = idx & 15;
        float o = 0.f;
        for (int s = 0; s <= t; ++s) o = fmaf(ret[t][s], V[s][k], o);
        o /= den[t];
        float mu = o;
        #pragma unroll
        for (int w = 8; w >= 1; w >>= 1) mu += __shfl_xor(mu, w, 16);
        mu *= (1.f / 16.f);
        float dv = o - mu;
        float var = dv * dv;
        #pragma unroll
        for (int w = 8; w >= 1; w >>= 1) var += __shfl_xor(var, w, 16);
        var *= (1.f / 16.f);
        float val = dv / sqrtf(var);
        if (isnan(val)) val = 0.f;
        val = 3.f * tanhf(val);
        xt[((size_t)((b * T_ + t) * N_ + n)) * DM_ + h * DK_ + k] = val;
    }
}

// ---------------- launch ----------------
extern "C" void kernel_launch(void* const* d_in, const int* in_sizes, int n_in,
                              void* d_out, int out_size, void* d_ws, size_t ws_size,
                              hipStream_t stream) {
    const float* inputs   = (const float*)d_in[0];
    const float* c_inputs = (const float*)d_in[1];
    const float* ml_w1    = (const float*)d_in[2];
    const float* ml_b1    = (const float*)d_in[3];
    const float* ml_w2    = (const float*)d_in[4];
    const float* ml_b2    = (const float*)d_in[5];
    const float* gdc_w1   = (const float*)d_in[6];
    const float* gdc_w2   = (const float*)d_in[7];
    const float* wg_w     = (const float*)d_in[8];
    const float* wg_b     = (const float*)d_in[9];
    const float* wo_w     = (const float*)d_in[10];
    const float* wo_b     = (const float*)d_in[11];
    const float* ln_g     = (const float*)d_in[12];
    const float* ln_b     = (const float*)d_in[13];
    float* out = (float*)d_out;

    const size_t hid_e = (size_t)MTOKP * DH_;   // ushort elems
    const size_t w2t_e = (size_t)OUT2 * DH_;    // ushort elems
    const size_t main_bytes = (2 * hid_e + 2 * w2t_e) * sizeof(unsigned short)
                            + ((size_t)MTOK * QKVC + (size_t)MTOK * DM_) * sizeof(float);

    if (ws_size >= main_bytes) {
        unsigned short* hh   = (unsigned short*)d_ws;
        unsigned short* hl   = hh + hid_e;
        unsigned short* w2th = hl + hid_e;
        unsigned short* w2tl = w2th + w2t_e;
        float* qkv = (float*)(w2tl + w2t_e);
        float* xt  = qkv + (size_t)MTOK * QKVC;

        k_hid2<<<dim3(MTOKP / 16), dim3(256), 0, stream>>>(c_inputs, ml_w1, ml_b1, hh, hl);
        k_split<<<dim3(OUT2 / 64, DH_ / 64), dim3(256), 0, stream>>>(ml_w2, w2th, w2tl);
        // 20 m-tiles x 48 n-tiles = 960 blocks of 1024 threads (last m-tile over-reads within d_ws; guarded)
        k_gemm<<<dim3(960), dim3(1024), 0, stream>>>(hh, hl, w2th, w2tl, ml_b2, inputs, qkv);
        k_ret4<<<dim3((N_ + 3) / 4, H_, B_), dim3(256), 0, stream>>>(qkv, xt);
        k_out4<<<dim3((MTOK + 3) / 4), dim3(256), 0, stream>>>(xt, inputs, gdc_w1, gdc_w2,
            wg_w, wg_b, wo_w, wo_b, ln_g, ln_b, out);
    } else {
        float* hid  = (float*)d_ws;
        float* xt   = hid + (size_t)MTOK * DH_;
        float* part = xt + (size_t)MTOK * DM_;
        const size_t fixed_f = (size_t)MTOK * DH_ + (size_t)MTOK * DM_;
        auto fits = [&](int ks) {
            return (fixed_f + (size_t)ks * MTOK * QKVC) * sizeof(float) <= ws_size;
        };
        k_hid<<<dim3(MTOK / 4), dim3(256), 0, stream>>>(c_inputs, ml_w1, ml_b1, hid);
        const int gx = (MTOK + BM - 1) / BM;
        if (fits(2)) {
            k_qkv<2><<<dim3(gx, 2, 2), dim3(256), 0, stream>>>(inputs, hid, ml_w2, ml_b2, part);
            k_ret<2><<<dim3(N_, H_, B_), dim3(64), 0, stream>>>(part, xt);
        } else {
            k_qkv<1><<<dim3(gx, 2, 1), dim3(256), 0, stream>>>(inputs, hid, ml_w2, ml_b2, part);
            k_ret<1><<<dim3(N_, H_, B_), dim3(64), 0, stream>>>(part, xt);
        }
        k_out4<<<dim3((MTOK + 3) / 4), dim3(256), 0, stream>>>(xt, inputs, gdc_w1, gdc_w2,
            wg_w, wg_b, wo_w, wo_b, ln_g, ln_b, out);
    }
}

// Round 15
// 131.877 us; speedup vs baseline: 7.6135x; 7.6135x over previous
//
#include <hip/hip_runtime.h>
#include <math.h>

#define B_ 2
#define T_ 12
#define N_ 207
#define DM_ 64
#define H_ 4
#define DK_ 16
#define DH_ 256
#define MTOK 4968       // B*T*N
#define MTOKP 4992      // padded to 39*128 (exact GEMM m-coverage)
#define OUT2 12288      // 3*H*DK*DM
#define QKVC 192        // 3*H*DK
#define RW 512          // interleaved row width in ushorts (256 k x {hi,lo})

typedef __bf16 bf16x8 __attribute__((ext_vector_type(8)));
typedef float f32x4 __attribute__((ext_vector_type(4)));
typedef unsigned short ushortx8 __attribute__((ext_vector_type(8)));

__device__ __forceinline__ unsigned short f2bf(float f) {
    union { float f; unsigned u; } v; v.f = f;
    unsigned r = v.u + 0x7fffu + ((v.u >> 16) & 1u);   // RNE
    return (unsigned short)(r >> 16);
}
__device__ __forceinline__ float bf2f(unsigned short b) {
    union { unsigned u; float f; } v; v.u = ((unsigned)b) << 16; return v.f;
}
__device__ __forceinline__ void gll16(const void* g, void* l) {
    __builtin_amdgcn_global_load_lds((const __attribute__((address_space(1))) void*)g,
                                     (__attribute__((address_space(3))) void*)l, 16, 0, 0);
}

// ---------------- Kernel A: hid interleaved hi/lo bf16 = split(relu(c_inputs @ ml_w1 + b1)) ----------------
// Row layout (RW=512 ushorts): [hi(k 0-7), lo(k 0-7), hi(k 8-15), lo(k 8-15), ...]
__global__ __launch_bounds__(256) void k_hid2(const float* __restrict__ cin,
                                              const float* __restrict__ w1,
                                              const float* __restrict__ b1,
                                              unsigned short* __restrict__ hid_i) {
    __shared__ float cs[16][DM_];
    const int t0 = blockIdx.x * 16;
    const int tid = threadIdx.x;
    #pragma unroll
    for (int r = 0; r < 4; ++r) {
        int idx = r * 256 + tid;
        int t = idx >> 6, d = idx & 63;
        int tok = t0 + t;
        cs[t][d] = (tok < MTOK) ? cin[(size_t)tok * DM_ + d] : 0.f;
    }
    __syncthreads();
    float a[16];
    #pragma unroll
    for (int t = 0; t < 16; ++t) a[t] = 0.f;
    for (int d = 0; d < DM_; ++d) {
        float wv = w1[d * DH_ + tid];
        #pragma unroll
        for (int t = 0; t < 16; ++t) a[t] = fmaf(cs[t][d], wv, a[t]);
    }
    float b = b1[tid];
    const int g = tid >> 3, pos = tid & 7;    // k-group, position
    #pragma unroll
    for (int t = 0; t < 16; ++t) {
        int tok = t0 + t;
        float val = (tok < MTOK) ? fmaxf(a[t] + b, 0.f) : 0.f;
        unsigned short hi = f2bf(val);
        hid_i[(size_t)tok * RW + g * 16 + pos]     = hi;
        hid_i[(size_t)tok * RW + g * 16 + 8 + pos] = f2bf(val - bf2f(hi));
    }
}

// ---------------- Kernel B: transpose + split w2 -> interleaved w2t_i [12288 x RW] ----------------
__global__ __launch_bounds__(256) void k_split(const float* __restrict__ w2,
                                               unsigned short* __restrict__ wi) {
    __shared__ float tbuf[64][72];
    const int tid = threadIdx.x;
    const int c0 = blockIdx.x * 64;
    const int j0 = blockIdx.y * 64;
    #pragma unroll
    for (int r = 0; r < 4; ++r) {
        int idx = r * 256 + tid;
        int j = idx >> 4, c4 = idx & 15;
        float4 v = *reinterpret_cast<const float4*>(w2 + (size_t)(j0 + j) * OUT2 + c0 + c4 * 4);
        *reinterpret_cast<float4*>(&tbuf[j][c4 * 4]) = v;
    }
    __syncthreads();
    #pragma unroll
    for (int r = 0; r < 2; ++r) {
        int slot = r * 256 + tid;
        int c = slot >> 3, j8 = slot & 7;
        ushortx8 Hv, Lv;
        #pragma unroll
        for (int e = 0; e < 8; ++e) {
            float f = tbuf[j8 * 8 + e][c];
            unsigned short h = f2bf(f);
            Hv[e] = h;
            Lv[e] = f2bf(f - bf2f(h));
        }
        size_t off = (size_t)(c0 + c) * RW + (size_t)(j0 + j8 * 8) * 2;   // hi block at j*2, lo at +8
        *reinterpret_cast<ushortx8*>(wi + off)     = Hv;
        *reinterpret_cast<ushortx8*>(wi + off + 8) = Lv;
    }
}

// ---------------- Kernel C: split-bf16 MFMA GEMM — 128x128, 4 waves, 4 blocks/CU, DENSE 128B staging ----------------
// A[4992 x RW] (hid interleaved), B[12288 x RW] (w2t interleaved). Wave grid 2m x 2n; wave-tile 64x64.
// 3744 blocks = 8 XCDs x (39 m x 12 n); B panel L2-resident. BK=32 slice = 128 B contiguous per row
// (hi+lo interleaved) -> every staged segment is a full, aligned 128 B L2 line (the single change vs R13).
// Chunk XOR swizzle (8 chunks/row): chunk' = chunk ^ (row&7), applied on global source AND LDS read.
__global__ __launch_bounds__(256, 4) void k_gemm(const unsigned short* __restrict__ Ai,
                                                 const unsigned short* __restrict__ Bi,
                                                 const float* __restrict__ b2,
                                                 const float* __restrict__ x,
                                                 float* __restrict__ qkv) {
    __shared__ __align__(16) unsigned short sA[8192], sB[8192];   // 128 rows x 64 ushorts (128 B)
    const int tid = threadIdx.x;
    // XCD-column swizzle: 3744 = 8 XCDs x (39 m x 12 n); n fastest within a chunk
    const int bid = blockIdx.x;
    const int xcd = bid & 7;
    const int r_ = bid >> 3;                      // 0..467
    const int m0 = (r_ / 12) * 128;               // 39 m-tiles
    const int n0 = (xcd * 12 + (r_ % 12)) * 128;  // 12 n-tiles per XCD
    const int wid = tid >> 6;                     // 0..3
    const int lane = tid & 63;
    const int l15 = lane & 15, l4 = lane >> 4;
    const int wm = wid >> 1, wn = wid & 1;        // 2m x 2n wave grid; wave-tile 64x64

    // ---- staging: slot s = inst*256 + tid; row = s>>3 (0..127), chunk = s&7 (16B chunks of the 128B slice)
    const int srow = tid >> 3;                    // 0..31 (+32 per instruction)
    const int sch  = tid & 7;
    const int gch  = sch ^ (srow & 7);            // pre-swizzled source chunk (row+32 keeps row&7)
    const unsigned short* pA = Ai + (size_t)(m0 + srow) * RW + gch * 8;
    const unsigned short* pB = Bi + (size_t)(n0 + srow) * RW + gch * 8;
    const size_t rstep = (size_t)32 * RW;         // +32 rows per instruction
    const int lbase = wid * 512;                  // wave-uniform LDS ushort base within an instruction

    // ---- fragment-read swizzle: row = wm*64+mi*16+l15 -> row&7 == l15&7
    const int rsw = l15 & 7;
    const int chHi = ((2 * l4) ^ rsw) * 8;        // ushort offset of hi 16B chunk
    const int chLo = ((2 * l4 + 1) ^ rsw) * 8;    // lo chunk

    f32x4 acc[4][4];
    const f32x4 zero = {0.f, 0.f, 0.f, 0.f};
    #pragma unroll
    for (int i = 0; i < 4; ++i)
        #pragma unroll
        for (int j = 0; j < 4; ++j) acc[i][j] = zero;

    for (int ks = 0; ks < 8; ++ks) {
        #pragma unroll
        for (int i = 0; i < 4; ++i) gll16(pA + i * rstep, &sA[i * 2048 + lbase]);
        #pragma unroll
        for (int i = 0; i < 4; ++i) gll16(pB + i * rstep, &sB[i * 2048 + lbase]);
        pA += 64; pB += 64;               // advance BK=32 (64 interleaved ushorts)
        __syncthreads();                  // drains vmcnt + lgkm; buffer ready

        bf16x8 ah[4], al[4];
        #pragma unroll
        for (int mi = 0; mi < 4; ++mi) {
            int rb = (wm * 64 + mi * 16 + l15) * 64;
            ah[mi] = *reinterpret_cast<const bf16x8*>(&sA[rb + chHi]);
            al[mi] = *reinterpret_cast<const bf16x8*>(&sA[rb + chLo]);
        }
        #pragma unroll
        for (int ni = 0; ni < 4; ++ni) {
            int nb = (wn * 64 + ni * 16 + l15) * 64;
            bf16x8 bh = *reinterpret_cast<const bf16x8*>(&sB[nb + chHi]);
            bf16x8 bl = *reinterpret_cast<const bf16x8*>(&sB[nb + chLo]);
            #pragma unroll
            for (int mi = 0; mi < 4; ++mi)
                acc[mi][ni] = __builtin_amdgcn_mfma_f32_16x16x32_bf16(ah[mi], bh, acc[mi][ni], 0, 0, 0);
            #pragma unroll
            for (int mi = 0; mi < 4; ++mi)
                acc[mi][ni] = __builtin_amdgcn_mfma_f32_16x16x32_bf16(ah[mi], bl, acc[mi][ni], 0, 0, 0);
            #pragma unroll
            for (int mi = 0; mi < 4; ++mi)
                acc[mi][ni] = __builtin_amdgcn_mfma_f32_16x16x32_bf16(al[mi], bh, acc[mi][ni], 0, 0, 0);
        }
        __syncthreads();                  // LDS reads done; safe to overwrite next iter
    }

    // epilogue: wave's 64 n-columns = one c-block; contract against x over d
    const int cg = (n0 >> 6) + wn;        // global c index (0..191)
    float b2v[4];
    #pragma unroll
    for (int ni = 0; ni < 4; ++ni) b2v[ni] = b2[cg * 64 + ni * 16 + l15];
    #pragma unroll
    for (int mi = 0; mi < 4; ++mi) {
        #pragma unroll
        for (int r = 0; r < 4; ++r) {
            int rl = wm * 64 + mi * 16 + l4 * 4 + r;   // C/D: row=(lane>>4)*4+reg, col=lane&15
            int gm = m0 + rl;
            int gmc = gm < MTOK ? gm : MTOK - 1;
            float v = 0.f;
            #pragma unroll
            for (int ni = 0; ni < 4; ++ni)
                v = fmaf(acc[mi][ni][r] + b2v[ni], x[(size_t)gmc * DM_ + ni * 16 + l15], v);
            #pragma unroll
            for (int sw = 1; sw < 16; sw <<= 1) v += __shfl_xor(v, sw, 16);
            if (l15 == 0 && gm < MTOK) qkv[(size_t)gm * QKVC + cg] = v;
        }
    }
}

// ---------------- Kernel D: retention + GroupNorm + 3*tanh — one wave per (b,n,h), no barriers ----------------
__global__ __launch_bounds__(256) void k_ret4(const float* __restrict__ qkv,
                                              float* __restrict__ xt) {
    const int tid = threadIdx.x;
    const int g = tid >> 6, lane = tid & 63;
    const int n = blockIdx.x * 4 + g;
    const int h = blockIdx.y;
    const int b = blockIdx.z;
    const bool act = (n < N_);
    __shared__ float Q[4][T_][DK_ + 1], K[4][T_][DK_ + 1], V[4][T_][DK_ + 1];
    __shared__ float ret[4][T_][T_ + 1];
    __shared__ float den[4][T_];
    if (act) {
        for (int idx = lane; idx < T_ * DK_; idx += 64) {
            int t = idx >> 4, k = idx & 15;
            size_t base = ((size_t)((b * T_ + t) * N_ + n)) * QKVC + h * DK_ + k;
            Q[g][t][k] = qkv[base];
            K[g][t][k] = qkv[base + 64];
            V[g][t][k] = qkv[base + 128];
        }
        const float r = 1.f - exp2f(-5.f - (float)h);
        for (int p = lane; p < T_ * T_; p += 64) {
            int t = p / T_, s = p - t * T_;
            float val = 0.f;
            if (s <= t) {
                float dot = 0.f;
                #pragma unroll
                for (int k = 0; k < DK_; ++k) dot = fmaf(Q[g][t][k], K[g][s][k], dot);
                float sum = 0.f, rp = 1.f;
                for (int i = 0; i <= t; ++i) { sum += rp; rp *= r; }
                float Dv = powf(r, (float)(t - s)) / sqrtf(sum);
                val = dot * 0.25f * cosf((float)(t - s)) * Dv;
            }
            ret[g][t][s] = val;
        }
        if (lane < T_) {
            float sm = 0.f;
            for (int j = 0; j < T_; ++j) sm += ret[g][lane][j];
            den[g][lane] = fmaxf(fabsf(sm), 1.f);
        }
        for (int idx = lane; idx < T_ * DK_; idx += 64) {
            int t = idx >> 4, k = idx & 15;
            float o = 0.f;
            for (int s = 0; s <= t; ++s) o = fmaf(ret[g][t][s], V[g][s][k], o);
            o /= den[g][t];
            float mu = o;
            #pragma unroll
            for (int w = 8; w >= 1; w >>= 1) mu += __shfl_xor(mu, w, 16);
            mu *= (1.f / 16.f);
            float dv = o - mu;
            float var = dv * dv;
            #pragma unroll
            for (int w = 8; w >= 1; w >>= 1) var += __shfl_xor(var, w, 16);
            var *= (1.f / 16.f);
            float val = dv / sqrtf(var);
            if (isnan(val)) val = 0.f;
            val = 3.f * tanhf(val);
            xt[((size_t)((b * T_ + t) * N_ + n)) * DM_ + h * DK_ + k] = val;
        }
    }
}

// ---------------- Kernel E: GDC + swish + out-proj + residual + LayerNorm — one wave per token ----------------
__global__ __launch_bounds__(256) void k_out4(const float* __restrict__ xt,
                                              const float* __restrict__ in,
                                              const float* __restrict__ gw1,
                                              const float* __restrict__ gw2,
                                              const float* __restrict__ wgw,
                                              const float* __restrict__ wgb,
                                              const float* __restrict__ wow,
                                              const float* __restrict__ wob,
                                              const float* __restrict__ lng,
                                              const float* __restrict__ lnb,
                                              float* __restrict__ out) {
    const int tid = threadIdx.x;
    const int w = tid >> 6;
    const int m = tid & 63;
    const int tok = blockIdx.x * 4 + w;
    const bool act = tok < MTOK;
    const int tokc = act ? tok : MTOK - 1;
    __shared__ float xsh[4][DM_], insh[4][DM_], zsh[4][DM_];
    xsh[w][m]  = xt[(size_t)tokc * DM_ + m];
    insh[w][m] = in[(size_t)tokc * DM_ + m];
    float ah[H_], sh[H_];
    #pragma unroll
    for (int h = 0; h < H_; ++h) {
        float a = 0.f, s = 0.f;
        #pragma unroll
        for (int k = 0; k < DK_; ++k) {
            float xv = xsh[w][h * DK_ + k];
            a = fmaf(xv, gw1[(h * DK_ + k) * DM_ + m], a);
            s = fmaf(xv, gw2[(h * DK_ + k) * DM_ + m], s);
        }
        ah[h] = a;
        sh[h] = fmaxf(s, 0.f);
    }
    float mx = fmaxf(fmaxf(sh[0], sh[1]), fmaxf(sh[2], sh[3]));
    float e0 = expf(sh[0] - mx), e1 = expf(sh[1] - mx);
    float e2 = expf(sh[2] - mx), e3 = expf(sh[3] - mx);
    float esum = e0 + e1 + e2 + e3;
    float g = (ah[0] * e0 + ah[1] * e1 + ah[2] * e2 + ah[3] * e3) / esum;
    float z = 0.f;
    for (int d = 0; d < DM_; ++d) z = fmaf(insh[w][d], wgw[d * DM_ + m], z);
    z += wgb[m];
    z *= g;
    z = z / (1.f + expf(-z));
    zsh[w][m] = z;
    float o = 0.f;
    for (int d = 0; d < DM_; ++d) o = fmaf(zsh[w][d], wow[d * DM_ + m], o);
    o += wob[m];
    float y = o + insh[w][m];
    float mu = y;
    #pragma unroll
    for (int xm = 32; xm >= 1; xm >>= 1) mu += __shfl_xor(mu, xm, 64);
    mu *= (1.f / 64.f);
    float dv = y - mu;
    float var = dv * dv;
    #pragma unroll
    for (int xm = 32; xm >= 1; xm >>= 1) var += __shfl_xor(var, xm, 64);
    var *= (1.f / 64.f);
    float res = dv / sqrtf(var + 1e-5f) * lng[m] + lnb[m];
    if (act) out[(size_t)tok * DM_ + m] = res;
}

// ---------------- fallback fp32 kernels (old path, if workspace too small) ----------------
__global__ __launch_bounds__(256) void k_hid(const float* __restrict__ cin,
                                             const float* __restrict__ w1,
                                             const float* __restrict__ b1,
                                             float* __restrict__ hid) {
    __shared__ float cs[4][DM_];
    const int t0 = blockIdx.x * 4;
    const int tid = threadIdx.x;
    {
        int t = tid >> 6, d = tid & 63;
        cs[t][d] = cin[(size_t)(t0 + t) * DM_ + d];
    }
    __syncthreads();
    float a0 = 0.f, a1 = 0.f, a2 = 0.f, a3 = 0.f;
    for (int d = 0; d < DM_; ++d) {
        float w = w1[d * DH_ + tid];
        a0 = fmaf(cs[0][d], w, a0);
        a1 = fmaf(cs[1][d], w, a1);
        a2 = fmaf(cs[2][d], w, a2);
        a3 = fmaf(cs[3][d], w, a3);
    }
    float b = b1[tid];
    hid[(size_t)(t0 + 0) * DH_ + tid] = fmaxf(a0 + b, 0.f);
    hid[(size_t)(t0 + 1) * DH_ + tid] = fmaxf(a1 + b, 0.f);
    hid[(size_t)(t0 + 2) * DH_ + tid] = fmaxf(a2 + b, 0.f);
    hid[(size_t)(t0 + 3) * DH_ + tid] = fmaxf(a3 + b, 0.f);
}

#define BM 192
#define BN 96
template <int KS>
__global__ __launch_bounds__(256, 2) void k_qkv(const float* __restrict__ x,
                                                const float* __restrict__ hid,
                                                const float* __restrict__ w2,
                                                const float* __restrict__ b2,
                                                float* __restrict__ part) {
    constexpr int JPB = DH_ / KS;
    __shared__ float4 xs4[BM * 16];
    __shared__ float4 ws4[BN * 16];
    const int tid = threadIdx.x;
    const int m0 = blockIdx.x * BM;
    const int c0 = blockIdx.y * BN;
    const int kz = blockIdx.z;
    const int cidx = tid & 15;
    const int midx = tid >> 4;
    #pragma unroll
    for (int i = 0; i < 12; ++i) {
        int e4 = tid + 256 * i;
        int m = e4 >> 4;
        int d4 = e4 & 15;
        int gm = m0 + m;
        float4 v = make_float4(0.f, 0.f, 0.f, 0.f);
        if (gm < MTOK) v = *reinterpret_cast<const float4*>(x + (size_t)gm * DM_ + d4 * 4);
        xs4[m * 16 + (d4 ^ (m & 15))] = v;
    }
    float acc[12][6];
    #pragma unroll
    for (int i = 0; i < 12; ++i)
        #pragma unroll
        for (int q = 0; q < 6; ++q) acc[i][q] = 0.f;
    const int jn = (kz == 0) ? (JPB + 1) : JPB;
    float4 st[6];
    {
        const float* src = w2 + (size_t)(kz * JPB) * OUT2 + c0 * DM_;
        #pragma unroll
        for (int i = 0; i < 6; ++i)
            st[i] = *reinterpret_cast<const float4*>(src + (tid + 256 * i) * 4);
    }
    #pragma unroll
    for (int i = 0; i < 6; ++i) {
        int t4 = tid + 256 * i;
        int c = t4 >> 4;
        int d4 = t4 & 15;
        ws4[c * 16 + (d4 ^ (c & 15))] = st[i];
    }
    __syncthreads();
    for (int jj = 0; jj < jn; ++jj) {
        const bool have_next = (jj + 1 < jn);
        if (have_next) {
            const bool nb = (kz == 0) && (jj + 1 == JPB);
            const float* src = nb ? (b2 + c0 * DM_)
                                  : (w2 + (size_t)(kz * JPB + jj + 1) * OUT2 + c0 * DM_);
            #pragma unroll
            for (int i = 0; i < 6; ++i)
                st[i] = *reinterpret_cast<const float4*>(src + (tid + 256 * i) * 4);
        }
        const bool bias_cur = (kz == 0) && (jj == JPB);
        const int jg = kz * JPB + jj;
        float hv[12];
        #pragma unroll
        for (int i = 0; i < 12; ++i) {
            int gm = m0 + midx + 16 * i;
            hv[i] = bias_cur ? 1.f : ((gm < MTOK) ? hid[(size_t)gm * DH_ + jg] : 0.f);
        }
        for (int d4 = 0; d4 < 16; ++d4) {
            float4 xa[12];
            #pragma unroll
            for (int i = 0; i < 12; ++i) {
                float4 v = xs4[(midx + 16 * i) * 16 + (d4 ^ midx)];
                v.x *= hv[i]; v.y *= hv[i]; v.z *= hv[i]; v.w *= hv[i];
                xa[i] = v;
            }
            #pragma unroll
            for (int q = 0; q < 6; ++q) {
                float4 wv = ws4[(cidx + 16 * q) * 16 + (d4 ^ cidx)];
                #pragma unroll
                for (int i = 0; i < 12; ++i) {
                    float t = acc[i][q];
                    t = fmaf(xa[i].x, wv.x, t);
                    t = fmaf(xa[i].y, wv.y, t);
                    t = fmaf(xa[i].z, wv.z, t);
                    t = fmaf(xa[i].w, wv.w, t);
                    acc[i][q] = t;
                }
            }
        }
        __syncthreads();
        if (have_next) {
            #pragma unroll
            for (int i = 0; i < 6; ++i) {
                int t4 = tid + 256 * i;
                int c = t4 >> 4;
                int d4 = t4 & 15;
                ws4[c * 16 + (d4 ^ (c & 15))] = st[i];
            }
        }
        __syncthreads();
    }
    float* dst = part + (size_t)kz * MTOK * QKVC;
    #pragma unroll
    for (int i = 0; i < 12; ++i) {
        int gm = m0 + midx + 16 * i;
        if (gm < MTOK) {
            #pragma unroll
            for (int q = 0; q < 6; ++q)
                dst[(size_t)gm * QKVC + c0 + cidx + 16 * q] = acc[i][q];
        }
    }
}

template <int KS>
__global__ __launch_bounds__(64) void k_ret(const float* __restrict__ part,
                                            float* __restrict__ xt) {
    const int n = blockIdx.x;
    const int h = blockIdx.y;
    const int b = blockIdx.z;
    const int tid = threadIdx.x;
    __shared__ float Q[T_][DK_ + 1], K[T_][DK_ + 1], V[T_][DK_ + 1];
    __shared__ float ret[T_][T_ + 1];
    __shared__ float den[T_];
    for (int idx = tid; idx < T_ * DK_; idx += 64) {
        int t = idx >> 4, k = idx & 15;
        size_t base = ((size_t)((b * T_ + t) * N_ + n)) * QKVC + h * DK_ + k;
        float q = 0.f, kk = 0.f, v = 0.f;
        #pragma unroll
        for (int p = 0; p < KS; ++p) {
            size_t off = (size_t)p * MTOK * QKVC + base;
            q  += part[off];
            kk += part[off + 64];
            v  += part[off + 128];
        }
        Q[t][k] = q; K[t][k] = kk; V[t][k] = v;
    }
    __syncthreads();
    const float r = 1.f - exp2f(-5.f - (float)h);
    for (int p = tid; p < T_ * T_; p += 64) {
        int t = p / T_, s = p - t * T_;
        float val = 0.f;
        if (s <= t) {
            float dot = 0.f;
            #pragma unroll
            for (int k = 0; k < DK_; ++k) dot = fmaf(Q[t][k], K[s][k], dot);
            float sum = 0.f, rp = 1.f;
            for (int i = 0; i <= t; ++i) { sum += rp; rp *= r; }
            float Dv = powf(r, (float)(t - s)) / sqrtf(sum);
            val = dot * 0.25f * cosf((float)(t - s)) * Dv;
        }
        ret[t][s] = val;
    }
    __syncthreads();
    if (tid < T_) {
        float sm = 0.f;
        for (int j = 0; j < T_; ++j) sm += ret[tid][j];
        den[tid] = fmaxf(fabsf(sm), 1.f);
    }
    __syncthreads();
    for (int idx = tid; idx < T_ * DK_; idx += 64) {
        int t = idx >> 4, k = idx & 15;
        float o = 0.f;
        for (int s = 0; s <= t; ++s) o = fmaf(ret[t][s], V[s][k], o);
        o /= den[t];
        float mu = o;
        #pragma unroll
        for (int w = 8; w >= 1; w >>= 1) mu += __shfl_xor(mu, w, 16);
        mu *= (1.f / 16.f);
        float dv = o - mu;
        float var = dv * dv;
        #pragma unroll
        for (int w = 8; w >= 1; w >>= 1) var += __shfl_xor(var, w, 16);
        var *= (1.f / 16.f);
        float val = dv / sqrtf(var);
        if (isnan(val)) val = 0.f;
        val = 3.f * tanhf(val);
        xt[((size_t)((b * T_ + t) * N_ + n)) * DM_ + h * DK_ + k] = val;
    }
}

// ---------------- launch ----------------
extern "C" void kernel_launch(void* const* d_in, const int* in_sizes, int n_in,
                              void* d_out, int out_size, void* d_ws, size_t ws_size,
                              hipStream_t stream) {
    const float* inputs   = (const float*)d_in[0];
    const float* c_inputs = (const float*)d_in[1];
    const float* ml_w1    = (const float*)d_in[2];
    const float* ml_b1    = (const float*)d_in[3];
    const float* ml_w2    = (const float*)d_in[4];
    const float* ml_b2    = (const float*)d_in[5];
    const float* gdc_w1   = (const float*)d_in[6];
    const float* gdc_w2   = (const float*)d_in[7];
    const float* wg_w     = (const float*)d_in[8];
    const float* wg_b     = (const float*)d_in[9];
    const float* wo_w     = (const float*)d_in[10];
    const float* wo_b     = (const float*)d_in[11];
    const float* ln_g     = (const float*)d_in[12];
    const float* ln_b     = (const float*)d_in[13];
    float* out = (float*)d_out;

    const size_t hid_e = (size_t)MTOKP * RW;    // ushort elems (interleaved)
    const size_t w2t_e = (size_t)OUT2 * RW;
    const size_t main_bytes = (hid_e + w2t_e) * sizeof(unsigned short)
                            + ((size_t)MTOK * QKVC + (size_t)MTOK * DM_) * sizeof(float);

    if (ws_size >= main_bytes) {
        unsigned short* hid_i = (unsigned short*)d_ws;
        unsigned short* w2t_i = hid_i + hid_e;
        float* qkv = (float*)(w2t_i + w2t_e);
        float* xt  = qkv + (size_t)MTOK * QKVC;

        k_hid2<<<dim3(MTOKP / 16), dim3(256), 0, stream>>>(c_inputs, ml_w1, ml_b1, hid_i);
        k_split<<<dim3(OUT2 / 64, DH_ / 64), dim3(256), 0, stream>>>(ml_w2, w2t_i);
        // 39 m-tiles x 96 n-tiles = 3744 blocks of 256 threads
        k_gemm<<<dim3(3744), dim3(256), 0, stream>>>(hid_i, w2t_i, ml_b2, inputs, qkv);
        k_ret4<<<dim3((N_ + 3) / 4, H_, B_), dim3(256), 0, stream>>>(qkv, xt);
        k_out4<<<dim3((MTOK + 3) / 4), dim3(256), 0, stream>>>(xt, inputs, gdc_w1, gdc_w2,
            wg_w, wg_b, wo_w, wo_b, ln_g, ln_b, out);
    } else {
        float* hid  = (float*)d_ws;
        float* xt   = hid + (size_t)MTOK * DH_;
        float* part = xt + (size_t)MTOK * DM_;
        const size_t fixed_f = (size_t)MTOK * DH_ + (size_t)MTOK * DM_;
        auto fits = [&](int ks) {
            return (fixed_f + (size_t)ks * MTOK * QKVC) * sizeof(float) <= ws_size;
        };
        k_hid<<<dim3(MTOK / 4), dim3(256), 0, stream>>>(c_inputs, ml_w1, ml_b1, hid);
        const int gx = (MTOK + BM - 1) / BM;
        if (fits(2)) {
            k_qkv<2><<<dim3(gx, 2, 2), dim3(256), 0, stream>>>(inputs, hid, ml_w2, ml_b2, part);
            k_ret<2><<<dim3(N_, H_, B_), dim3(64), 0, stream>>>(part, xt);
        } else {
            k_qkv<1><<<dim3(gx, 2, 1), dim3(256), 0, stream>>>(inputs, hid, ml_w2, ml_b2, part);
            k_ret<1><<<dim3(N_, H_, B_), dim3(64), 0, stream>>>(part, xt);
        }
        k_out4<<<dim3((MTOK + 3) / 4), dim3(256), 0, stream>>>(xt, inputs, gdc_w1, gdc_w2,
            wg_w, wg_b, wo_w, wo_b, ln_g, ln_b, out);
    }
}